// Round 1
// baseline (4638.166 us; speedup 1.0000x reference)
//
#include <hip/hip_runtime.h>

typedef unsigned short u16;
typedef unsigned int u32;
typedef short s16x8 __attribute__((ext_vector_type(8)));
typedef float f32x4 __attribute__((ext_vector_type(4)));

#define T_LEN 512
#define BTH 2097152  // 16*512*256

__device__ __forceinline__ u16 f2bf(float f) {
  u32 u = __float_as_uint(f);
  u32 r = (u + 0x7FFFu + ((u >> 16) & 1u)) >> 16;  // RNE
  return (u16)r;
}
__device__ __forceinline__ float bf2f(u16 u) {
  return __uint_as_float(((u32)u) << 16);
}
__device__ __forceinline__ float sigm_(float x) { return 1.f / (1.f + __expf(-x)); }
__device__ __forceinline__ float tanh_(float x) {
  x = fminf(15.f, fmaxf(-15.f, x));
  float e = __expf(2.f * x);
  return (e - 1.f) / (e + 1.f);
}
__device__ __forceinline__ void dot2(u32 w, float h0, float h1, float& acc) {
  acc += bf2f((u16)(w & 0xFFFFu)) * h0;
  acc += bf2f((u16)(w >> 16)) * h1;
}

// x [b][t][d] f32 -> xb [(t*16+b)][d] bf16
__global__ void cast_x_kernel(const float* __restrict__ x, u16* __restrict__ xb) {
  int e = blockIdx.x * 256 + threadIdx.x;  // < 2097152
  int d = e & 255;
  int r = e >> 8;  // b*512 + t
  int bb = r >> 9, t = r & 511;
  xb[(size_t)((t << 4) | bb) * 256 + d] = f2bf(x[e]);
}

__global__ void cast_w_kernel(const float* __restrict__ w, u16* __restrict__ o, int n) {
  int e = blockIdx.x * 256 + threadIdx.x;
  if (e < n) o[e] = f2bf(w[e]);
}

// B_w [o][d][h] f32 -> Btt [(o*256+h)][d] bf16  (n-major for GEMM B-operand)
__global__ void transpose_b_kernel(const float* __restrict__ Bw, u16* __restrict__ Btt) {
  __shared__ float T[64][65];
  const int o = blockIdx.y;
  const int d0 = (blockIdx.x >> 2) * 64;
  const int h0 = (blockIdx.x & 3) * 64;
  const int tid = threadIdx.x;
  const float* src = Bw + (size_t)o * 65536;
#pragma unroll
  for (int k = 0; k < 16; ++k) {
    int idx = tid + k * 256;
    int rr = idx >> 6, cc = idx & 63;
    T[rr][cc] = src[(size_t)(d0 + rr) * 256 + h0 + cc];
  }
  __syncthreads();
#pragma unroll
  for (int k = 0; k < 16; ++k) {
    int idx = tid + k * 256;
    int rr = idx >> 6, cc = idx & 63;
    Btt[(size_t)(o * 256 + h0 + rr) * 256 + d0 + cc] = f2bf(T[cc][rr]);
  }
}

// C[m][n] = A[m][:] . Bm[n][:]   (A,Bm bf16 row-major over K=256; fp32 accum)
// OF32: write float + (bias0+bias1)[n]; else write bf16.
template <bool OF32>
__global__ __launch_bounds__(256) void gemm_nt(
    const u16* __restrict__ A, const u16* __restrict__ Bm,
    u16* __restrict__ Cb, float* __restrict__ Cf, int N,
    const float* __restrict__ bias0, const float* __restrict__ bias1) {
  __shared__ u16 As[128][40];  // +8 pad: keeps ds_read_b128 conflicts <=2-way (free)
  __shared__ u16 Bs[128][40];
  const int tid = threadIdx.x;
  const int m0 = blockIdx.x * 128;
  const int n0 = blockIdx.y * 128;
  const int wave = tid >> 6, lane = tid & 63;
  const int wm = (wave >> 1) * 64, wn = (wave & 1) * 64;
  const int qm = lane & 15, quad = lane >> 4;
  f32x4 acc[4][4] = {};

  for (int k0 = 0; k0 < 256; k0 += 32) {
    __syncthreads();
#pragma unroll
    for (int ii = 0; ii < 2; ++ii) {
      int cch = tid + ii * 256;  // 512 16B-chunks per tile
      int row = cch >> 2, col = (cch & 3) * 8;
      *(uint4*)&As[row][col] = *(const uint4*)(A + (size_t)(m0 + row) * 256 + k0 + col);
      *(uint4*)&Bs[row][col] = *(const uint4*)(Bm + (size_t)(n0 + row) * 256 + k0 + col);
    }
    __syncthreads();
    s16x8 af[4], bfr[4];
#pragma unroll
    for (int i = 0; i < 4; ++i) af[i] = *(const s16x8*)&As[wm + i * 16 + qm][quad * 8];
#pragma unroll
    for (int j = 0; j < 4; ++j) bfr[j] = *(const s16x8*)&Bs[wn + j * 16 + qm][quad * 8];
#pragma unroll
    for (int i = 0; i < 4; ++i)
#pragma unroll
      for (int j = 0; j < 4; ++j)
        acc[i][j] = __builtin_amdgcn_mfma_f32_16x16x32_bf16(af[i], bfr[j], acc[i][j], 0, 0, 0);
  }
#pragma unroll
  for (int i = 0; i < 4; ++i) {
    int rg = m0 + wm + i * 16 + quad * 4;  // C/D: row = quad*4+reg, col = lane&15
#pragma unroll
    for (int j = 0; j < 4; ++j) {
      int cg = n0 + wn + j * 16 + qm;
      float bias = 0.f;
      if (OF32) bias = bias0[cg] + bias1[cg];
#pragma unroll
      for (int r = 0; r < 4; ++r) {
        float v = acc[i][j][r] + bias;
        size_t idx = (size_t)(rg + r) * (size_t)N + cg;
        if (OF32) Cf[idx] = v; else Cb[idx] = f2bf(v);
      }
    }
  }
}

// Persistent scan: 128 blocks = 16 batches x 8 o-slices of 32. 512 thr/block:
// group of 16 lanes per output o (16-way K-split + shuffle reduce). One
// per-batch monotonic-counter barrier per step (8 arrivals), agent scope.
#define YADDR(tt) ((const uint4*)(Y + ((size_t)((tt) - t0) * 16 + b) * 65536 + ((size_t)o << 8) + (s << 4)))
__global__ __launch_bounds__(512) void scan_kernel(
    const u16* __restrict__ Y, const float* __restrict__ wx,
    const float* __restrict__ Uw, const float* __restrict__ Bb,
    float* hbuf, float* cbuf, int* bar, float* __restrict__ out,
    int t0, int Tc) {
  __shared__ u16 Us[4 * 32 * 256];  // 64 KB: U rows {gate*256+o} for this o-slice
  const int tid = threadIdx.x;
  const int b = blockIdx.x >> 3;
  const int obase = (blockIdx.x & 7) * 32;
  for (int e = tid; e < 4 * 32 * 256; e += 512) {
    int gate = e >> 13, rem = e & 8191, oo = rem >> 8, h = rem & 255;
    Us[e] = f2bf(Uw[(size_t)((gate << 8) + obase + oo) * 256 + h]);
  }
  const int s = tid & 15;
  const int oo = tid >> 4;  // 0..31
  const int o = obase + oo;
  float c = cbuf[(b << 8) + o];
  const float bbias = Bb[o];
  __syncthreads();

  const int tend = t0 + Tc;
  uint4 ya = YADDR(t0)[0], yb = YADDR(t0)[1];
  const float* wxp0 = wx + ((size_t)t0 * 16 + b) * 1024 + o;
  float w0 = wxp0[0], w1 = wxp0[256], w2 = wxp0[512], w3 = wxp0[768];
  float hlast = 0.f;

  for (int t = t0; t < tend; ++t) {
    // prefetch next step's x-dependent data (independent of barrier)
    int tn = (t + 1 < tend) ? (t + 1) : t;
    const uint4* np = YADDR(tn);
    uint4 na = np[0], nb = np[1];
    const float* nwp = wx + ((size_t)tn * 16 + b) * 1024 + o;
    float nw0 = nwp[0], nw1 = nwp[256], nw2 = nwp[512], nw3 = nwp[768];

    const float* hcur = hbuf + ((t & 1) << 12) + (b << 8) + (s << 4);
    float hv[16];
#pragma unroll
    for (int j = 0; j < 16; ++j)
      hv[j] = __hip_atomic_load(hcur + j, __ATOMIC_RELAXED, __HIP_MEMORY_SCOPE_AGENT);

    float yd = 0.f;
    dot2(ya.x, hv[0], hv[1], yd);  dot2(ya.y, hv[2], hv[3], yd);
    dot2(ya.z, hv[4], hv[5], yd);  dot2(ya.w, hv[6], hv[7], yd);
    dot2(yb.x, hv[8], hv[9], yd);  dot2(yb.y, hv[10], hv[11], yd);
    dot2(yb.z, hv[12], hv[13], yd); dot2(yb.w, hv[14], hv[15], yd);

    float gs[4];
#pragma unroll
    for (int g = 0; g < 4; ++g) {
      const uint4* up = (const uint4*)(Us + g * 8192 + (oo << 8) + (s << 4));
      uint4 ua = up[0], ub = up[1];
      float a = 0.f;
      dot2(ua.x, hv[0], hv[1], a);  dot2(ua.y, hv[2], hv[3], a);
      dot2(ua.z, hv[4], hv[5], a);  dot2(ua.w, hv[6], hv[7], a);
      dot2(ub.x, hv[8], hv[9], a);  dot2(ub.y, hv[10], hv[11], a);
      dot2(ub.z, hv[12], hv[13], a); dot2(ub.w, hv[14], hv[15], a);
      gs[g] = a;
    }
#pragma unroll
    for (int mk = 1; mk < 16; mk <<= 1) {
      yd += __shfl_xor(yd, mk, 16);
      gs[0] += __shfl_xor(gs[0], mk, 16);
      gs[1] += __shfl_xor(gs[1], mk, 16);
      gs[2] += __shfl_xor(gs[2], mk, 16);
      gs[3] += __shfl_xor(gs[3], mk, 16);
    }
    float gi = sigm_(gs[0] + w0);
    float gf = sigm_(gs[1] + w1);
    float go = sigm_(gs[2] + w2);
    float gg = tanh_(gs[3] + w3);
    float mm = tanh_(yd + bbias);
    c = gf * c + gi * gg + 0.1f * mm;
    float hn = go * tanh_(c);
    hlast = hn;
    if (s == 0) {
      out[((size_t)b * 512 + t) * 256 + o] = hn;
      __hip_atomic_store(hbuf + (((t + 1) & 1) << 12) + (b << 8) + o, hn,
                         __ATOMIC_RELAXED, __HIP_MEMORY_SCOPE_AGENT);
    }
    ya = na; yb = nb;
    w0 = nw0; w1 = nw1; w2 = nw2; w3 = nw3;
    __syncthreads();  // all waves' stores retired (vmcnt drained before s_barrier)
    if (tid == 0) {
      __hip_atomic_fetch_add(&bar[b << 5], 1, __ATOMIC_RELEASE, __HIP_MEMORY_SCOPE_AGENT);
      const int target = (t + 1) << 3;  // 8 blocks per batch, monotonic
      while (__hip_atomic_load(&bar[b << 5], __ATOMIC_ACQUIRE, __HIP_MEMORY_SCOPE_AGENT) < target)
        __builtin_amdgcn_s_sleep(1);
    }
    __syncthreads();
  }
  if (s == 0) {
    cbuf[(b << 8) + o] = c;
    out[(size_t)BTH + (b << 8) + o] = hlast;           // final h
    out[(size_t)BTH + 4096 + (b << 8) + o] = c;        // final c
  }
}

extern "C" void kernel_launch(void* const* d_in, const int* in_sizes, int n_in,
                              void* d_out, int out_size, void* d_ws, size_t ws_size,
                              hipStream_t stream) {
  const float* x  = (const float*)d_in[0];
  const float* Ww = (const float*)d_in[1];
  const float* Wb = (const float*)d_in[2];
  const float* Uw = (const float*)d_in[3];
  const float* Ub = (const float*)d_in[4];
  const float* Bw = (const float*)d_in[5];
  const float* Bb = (const float*)d_in[6];
  float* out = (float*)d_out;

  char* ws = (char*)d_ws;
  const size_t WX_B  = (size_t)512 * 16 * 1024 * 4;  // 33.5 MB
  const size_t XB_B  = (size_t)8192 * 256 * 2;       // 4.2 MB
  const size_t BTT_B = (size_t)65536 * 256 * 2;      // 33.5 MB
  const size_t WBT_B = (size_t)1024 * 256 * 2;       // 0.5 MB
  const size_t ST_B  = 32768 + 16384 + 2048;         // hbuf + cbuf + bar
  const size_t fixedB = WX_B + XB_B + BTT_B + WBT_B + ST_B;
  size_t avail = (ws_size > fixedB) ? (ws_size - fixedB) : 0;
  long Tc = (long)(avail / 2097152);  // Y bytes per timestep (bf16)
  if (Tc > 512) Tc = 512;
  Tc &= ~7L;
  if (Tc < 8) Tc = 8;

  u16* Y      = (u16*)ws;
  size_t YB   = (size_t)Tc * 2097152;
  float* wx   = (float*)(ws + YB);
  u16* xb     = (u16*)(ws + YB + WX_B);
  u16* Btt    = (u16*)(ws + YB + WX_B + XB_B);
  u16* Wbt    = (u16*)(ws + YB + WX_B + XB_B + BTT_B);
  float* hbuf = (float*)(ws + YB + WX_B + XB_B + BTT_B + WBT_B);
  float* cbuf = hbuf + 8192;
  int* bar    = (int*)(cbuf + 4096);

  hipMemsetAsync(hbuf, 0, ST_B, stream);  // h0=c0=0, barrier counters=0
  cast_x_kernel<<<8192, 256, 0, stream>>>(x, xb);
  cast_w_kernel<<<1024, 256, 0, stream>>>(Ww, Wbt, 262144);
  transpose_b_kernel<<<dim3(16, 256), 256, 0, stream>>>(Bw, Btt);
  // Wx (+W_b+U_b) in fp32 out: reuse GEMM, N=1024
  gemm_nt<true><<<dim3(64, 8), 256, 0, stream>>>(xb, Wbt, nullptr, wx, 1024, Wb, Ub);

  for (int t0 = 0; t0 < 512; t0 += (int)Tc) {
    int Tcur = (512 - t0 < (int)Tc) ? (512 - t0) : (int)Tc;
    gemm_nt<false><<<dim3(Tcur * 16 / 128, 512), 256, 0, stream>>>(
        xb + (size_t)t0 * 16 * 256, Btt, Y, nullptr, 65536, nullptr, nullptr);
    scan_kernel<<<128, 512, 0, stream>>>(Y, wx, Uw, Bb, hbuf, cbuf, bar, out, t0, Tcur);
  }
}